// Round 1
// baseline (816.024 us; speedup 1.0000x reference)
//
#include <hip/hip_runtime.h>
#include <hip/hip_bf16.h>
#include <math.h>

#define NNODES 50000
#define NEDGES 600000
#define ETOT   (NEDGES + NNODES)
#define HID    128
#define NGRAPH 64
#define SLOPE  0.2f

// ---------- wave (64-lane) reductions ----------
__device__ __forceinline__ float wave_sum(float v) {
    #pragma unroll
    for (int m = 32; m >= 1; m >>= 1) v += __shfl_xor(v, m, 64);
    return v;
}
__device__ __forceinline__ float wave_max(float v) {
    #pragma unroll
    for (int m = 32; m >= 1; m >>= 1) v = fmaxf(v, __shfl_xor(v, m, 64));
    return v;
}

// ---------- c_s = W1 . as1, c_d = W1 . ad1 (layer-1 scalars) ----------
__global__ void k_dots(const float* __restrict__ W1, const float* __restrict__ as1,
                       const float* __restrict__ ad1, float* __restrict__ cbuf) {
    int l = threadIdx.x;  // 64 threads
    float w0 = W1[l], w1 = W1[l + 64];
    float ds = w0 * as1[l] + w1 * as1[l + 64];
    float dd = w0 * ad1[l] + w1 * ad1[l + 64];
    ds = wave_sum(ds); dd = wave_sum(dd);
    if (l == 0) { cbuf[0] = ds; cbuf[1] = dd; }
}

// ---------- CSR build: histogram over dst ----------
__global__ void k_hist(const int* __restrict__ ei, int* __restrict__ cnt) {
    int e = blockIdx.x * blockDim.x + threadIdx.x;
    if (e >= ETOT) return;
    int d = (e < NEDGES) ? ei[NEDGES + e] : (e - NEDGES);
    atomicAdd(&cnt[d], 1);
}

// ---------- scan stage A: per-1024-chunk exclusive scan ----------
__global__ void k_scanA(const int* __restrict__ cnt, int* __restrict__ tmp,
                        int* __restrict__ blockSums, int n) {
    __shared__ int warpSums[4];
    int t = threadIdx.x;                  // 256 threads
    int base = blockIdx.x * 1024 + t * 4;
    int v0 = (base + 0 < n) ? cnt[base + 0] : 0;
    int v1 = (base + 1 < n) ? cnt[base + 1] : 0;
    int v2 = (base + 2 < n) ? cnt[base + 2] : 0;
    int v3 = (base + 3 < n) ? cnt[base + 3] : 0;
    // inclusive within thread
    v1 += v0; v2 += v1; v3 += v2;
    int tsum = v3;
    int lane = t & 63, w = t >> 6;
    int sc = tsum;
    #pragma unroll
    for (int d = 1; d < 64; d <<= 1) {
        int o = __shfl_up(sc, d, 64);
        if (lane >= d) sc += o;
    }
    if (lane == 63) warpSums[w] = sc;
    __syncthreads();
    int woff = 0;
    for (int i = 0; i < w; i++) woff += warpSums[i];
    int texcl = woff + sc - tsum;  // exclusive prefix for this thread's first element
    if (base + 0 < n) tmp[base + 0] = texcl;
    if (base + 1 < n) tmp[base + 1] = texcl + v0;
    if (base + 2 < n) tmp[base + 2] = texcl + v1;
    if (base + 3 < n) tmp[base + 3] = texcl + v2;
    if (t == 255) blockSums[blockIdx.x] = woff + sc;
}

// ---------- scan stage B: serial scan of block sums ----------
__global__ void k_scanB(const int* __restrict__ bs, int* __restrict__ bo, int nb) {
    if (threadIdx.x == 0) {
        int acc = 0;
        for (int i = 0; i < nb; i++) { bo[i] = acc; acc += bs[i]; }
    }
}

// ---------- scan stage C: add block offsets -> row_ptr ----------
__global__ void k_scanC(const int* __restrict__ tmp, const int* __restrict__ bo,
                        int* __restrict__ rp, int n) {
    int t = threadIdx.x;
    int base = blockIdx.x * 1024 + t * 4;
    int add = bo[blockIdx.x];
    #pragma unroll
    for (int j = 0; j < 4; j++)
        if (base + j < n) rp[base + j] = tmp[base + j] + add;
    if (blockIdx.x == 0 && t == 0) rp[n] = ETOT;
}

// ---------- scatter edges into dst-grouped order ----------
__global__ void k_scatter(const int* __restrict__ ei, const int* __restrict__ rp,
                          int* __restrict__ cur, int* __restrict__ ssrc) {
    int e = blockIdx.x * blockDim.x + threadIdx.x;
    if (e >= ETOT) return;
    int s, d;
    if (e < NEDGES) { s = ei[e]; d = ei[NEDGES + e]; }
    else            { s = e - NEDGES; d = s; }
    int pos = rp[d] + atomicAdd(&cur[d], 1);
    ssrc[pos] = s;
}

// ---------- layer-1 aggregation (scalar per dst) ----------
__global__ void k_l1(const float* __restrict__ x, const int* __restrict__ rp,
                     const int* __restrict__ ssrc, const float* __restrict__ cbuf,
                     float* __restrict__ sd) {
    int d = blockIdx.x * blockDim.x + threadIdx.x;
    if (d >= NNODES) return;
    float cs = cbuf[0], cd = cbuf[1];
    float ald = x[d] * cd;
    int beg = rp[d], end = rp[d + 1];
    float m = -3.4e38f;
    for (int e = beg; e < end; e++) {
        float a = fmaf(x[ssrc[e]], cs, ald);
        a = a > 0.f ? a : SLOPE * a;
        m = fmaxf(m, a);
    }
    float den = 0.f, acc = 0.f;
    for (int e = beg; e < end; e++) {
        float xs = x[ssrc[e]];
        float a = fmaf(xs, cs, ald);
        a = a > 0.f ? a : SLOPE * a;
        float w = __expf(a - m);
        den += w; acc += w * xs;
    }
    sd[d] = acc / den;
}

// ---------- layer-1 expand: h1[i,j] = relu(s_i * W1[j] + b1[j]) ----------
__global__ void k_out1(const float* __restrict__ sd, const float* __restrict__ W1,
                       const float* __restrict__ b1, float* __restrict__ h) {
    int idx = blockIdx.x * blockDim.x + threadIdx.x;  // NNODES*32 threads
    int i = idx >> 5, c4 = (idx & 31) * 4;
    if (i >= NNODES) return;
    float s = sd[i];
    float4 w = *(const float4*)(W1 + c4);
    float4 b = *(const float4*)(b1 + c4);
    float4 o;
    o.x = fmaxf(fmaf(s, w.x, b.x), 0.f);
    o.y = fmaxf(fmaf(s, w.y, b.y), 0.f);
    o.z = fmaxf(fmaf(s, w.z, b.z), 0.f);
    o.w = fmaxf(fmaf(s, w.w, b.w), 0.f);
    *(float4*)(h + i * HID + c4) = o;
}

// ---------- fp32 GEMM: C[nrows x 128] = H[nrows x 128] * W[128 x 128] ----------
__launch_bounds__(256)
__global__ void k_gemm(const float* __restrict__ H, const float* __restrict__ W,
                       float* __restrict__ C, int nrows) {
    __shared__ float Hs[64 * 16];
    __shared__ float Ws[16 * 128];
    int t = threadIdx.x;
    int tx = t & 31, ty = t >> 5;
    int row0 = blockIdx.x * 64;
    float acc[8][4];
    #pragma unroll
    for (int i = 0; i < 8; i++)
        #pragma unroll
        for (int j = 0; j < 4; j++) acc[i][j] = 0.f;

    for (int kc = 0; kc < 128; kc += 16) {
        {   // stage H tile 64x16
            int r = t >> 2, kg = (t & 3) * 4;
            int gr = row0 + r;
            float4 v = make_float4(0.f, 0.f, 0.f, 0.f);
            if (gr < nrows) v = *(const float4*)(H + gr * 128 + kc + kg);
            *(float4*)(Hs + r * 16 + kg) = v;
        }
        #pragma unroll
        for (int q = 0; q < 2; q++) {  // stage W tile 16x128
            int f = t + q * 256;
            int kk = f >> 5, c4 = (f & 31) * 4;
            *(float4*)(Ws + kk * 128 + c4) = *(const float4*)(W + (kc + kk) * 128 + c4);
        }
        __syncthreads();
        #pragma unroll
        for (int kk = 0; kk < 16; kk++) {
            float4 wv = *(const float4*)(Ws + kk * 128 + tx * 4);
            #pragma unroll
            for (int i = 0; i < 8; i++) {
                float hv = Hs[(ty * 8 + i) * 16 + kk];
                acc[i][0] = fmaf(hv, wv.x, acc[i][0]);
                acc[i][1] = fmaf(hv, wv.y, acc[i][1]);
                acc[i][2] = fmaf(hv, wv.z, acc[i][2]);
                acc[i][3] = fmaf(hv, wv.w, acc[i][3]);
            }
        }
        __syncthreads();
    }
    #pragma unroll
    for (int i = 0; i < 8; i++) {
        int gr = row0 + ty * 8 + i;
        if (gr < nrows) {
            float4 o = make_float4(acc[i][0], acc[i][1], acc[i][2], acc[i][3]);
            *(float4*)(C + gr * 128 + tx * 4) = o;
        }
    }
}

// ---------- attention logits: al_s = xp.a_src, al_d = xp.a_dst (wave/node) ----------
__global__ void k_al(const float* __restrict__ xp, const float* __restrict__ as_,
                     const float* __restrict__ ad_, float* __restrict__ als,
                     float* __restrict__ ald) {
    int wid = threadIdx.x >> 6, lane = threadIdx.x & 63;
    int node = blockIdx.x * 4 + wid;
    if (node >= NNODES) return;
    float v0 = xp[node * 128 + lane], v1 = xp[node * 128 + 64 + lane];
    float ds = v0 * as_[lane] + v1 * as_[lane + 64];
    float dd = v0 * ad_[lane] + v1 * ad_[lane + 64];
    ds = wave_sum(ds); dd = wave_sum(dd);
    if (lane == 0) { als[node] = ds; ald[node] = dd; }
}

// ---------- GAT aggregation (wave per dst), fused +b and relu ----------
__launch_bounds__(256)
__global__ void k_agg(const float* __restrict__ xp, const float* __restrict__ als,
                      const float* __restrict__ ald, const int* __restrict__ rp,
                      const int* __restrict__ ssrc, const float* __restrict__ b,
                      float* __restrict__ hout) {
    int wid = threadIdx.x >> 6, lane = threadIdx.x & 63;
    int d = blockIdx.x * 4 + wid;
    if (d >= NNODES) return;
    int beg = rp[d], end = rp[d + 1];
    float adv = ald[d];
    // phase 1: max over incoming alphas (lanes parallel over edges)
    float m = -3.4e38f;
    for (int e = beg + lane; e < end; e += 64) {
        float a = als[ssrc[e]] + adv;
        a = a > 0.f ? a : SLOPE * a;
        m = fmaxf(m, a);
    }
    m = wave_max(m);
    // phase 2: serial over edges, lanes cover 128 channels as float2
    float den = 0.f;
    float2 acc = make_float2(0.f, 0.f);
    for (int e = beg; e < end; e++) {
        int s = ssrc[e];
        float a = als[s] + adv;
        a = a > 0.f ? a : SLOPE * a;
        float w = __expf(a - m);
        den += w;
        float2 v = *(const float2*)(xp + s * 128 + lane * 2);
        acc.x = fmaf(w, v.x, acc.x);
        acc.y = fmaf(w, v.y, acc.y);
    }
    float inv = 1.f / den;
    float2 bb = *(const float2*)(b + lane * 2);
    float2 o;
    o.x = fmaxf(fmaf(acc.x, inv, bb.x), 0.f);
    o.y = fmaxf(fmaf(acc.y, inv, bb.y), 0.f);
    *(float2*)(hout + d * 128 + lane * 2) = o;
}

// ---------- global mean pool (atomic accumulate) ----------
__global__ void k_pool(const float* __restrict__ h, const int* __restrict__ batch,
                       float* __restrict__ pool, float* __restrict__ gcnt) {
    int wid = threadIdx.x >> 6, lane = threadIdx.x & 63;
    int i = blockIdx.x * 4 + wid;
    if (i >= NNODES) return;
    int g = batch[i];
    float2 v = *(const float2*)(h + i * 128 + lane * 2);
    atomicAdd(&pool[g * 128 + lane * 2], v.x);
    atomicAdd(&pool[g * 128 + lane * 2 + 1], v.y);
    if (lane == 0) atomicAdd(&gcnt[g], 1.f);
}

// ---------- final linear + sigmoid ----------
__global__ void k_final(const float* __restrict__ pool, const float* __restrict__ gcnt,
                        const float* __restrict__ Wlin, const float* __restrict__ blin,
                        float* __restrict__ out) {
    int t = threadIdx.x;  // 128 threads
    int g = t >> 1, k = t & 1;
    float c = fmaxf(gcnt[g], 1.f);
    float acc = 0.f;
    for (int j = 0; j < 128; j++) acc += pool[g * 128 + j] * Wlin[j * 2 + k];
    acc = acc / c + blin[k];
    out[g * 2 + k] = 1.f / (1.f + __expf(-acc));
}

extern "C" void kernel_launch(void* const* d_in, const int* in_sizes, int n_in,
                              void* d_out, int out_size, void* d_ws, size_t ws_size,
                              hipStream_t stream) {
    const float* x    = (const float*)d_in[0];
    const int*   ei   = (const int*)d_in[1];
    const int*   batch= (const int*)d_in[2];
    const float* W1   = (const float*)d_in[3];
    const float* as1  = (const float*)d_in[4];
    const float* ad1  = (const float*)d_in[5];
    const float* b1   = (const float*)d_in[6];
    const float* W2   = (const float*)d_in[7];
    const float* as2  = (const float*)d_in[8];
    const float* ad2  = (const float*)d_in[9];
    const float* b2   = (const float*)d_in[10];
    const float* W3   = (const float*)d_in[11];
    const float* as3  = (const float*)d_in[12];
    const float* ad3  = (const float*)d_in[13];
    const float* b3   = (const float*)d_in[14];
    const float* Wlin = (const float*)d_in[15];
    const float* blin = (const float*)d_in[16];
    float* out = (float*)d_out;

    // ---- workspace layout (bytes) ----
    char* ws = (char*)d_ws;
    size_t off = 0;
    float* bufA   = (float*)(ws + off); off += (size_t)NNODES * HID * 4;   // 25.6 MB
    float* bufB   = (float*)(ws + off); off += (size_t)NNODES * HID * 4;   // 25.6 MB
    float* als    = (float*)(ws + off); off += NNODES * 4;
    float* ald    = (float*)(ws + off); off += NNODES * 4;
    int*   rp     = (int*)(ws + off);   off += (NNODES + 16) * 4;
    int*   tmp    = (int*)(ws + off);   off += NNODES * 4;
    int*   bsums  = (int*)(ws + off);   off += 64 * 4;
    int*   boffs  = (int*)(ws + off);   off += 64 * 4;
    int*   ssrc   = (int*)(ws + off);   off += (size_t)ETOT * 4;
    // zeroed region (single memset): cnt, cur, pool, gcnt
    char*  zbase  = ws + off;
    int*   cnt    = (int*)(ws + off);   off += NNODES * 4;
    int*   cur    = (int*)(ws + off);   off += NNODES * 4;
    float* pool   = (float*)(ws + off); off += NGRAPH * HID * 4;
    float* gcnt   = (float*)(ws + off); off += 64 * 4;
    size_t zbytes = (size_t)((char*)(ws + off) - zbase);
    float* cbuf   = (float*)(ws + off); off += 64;   // c_s, c_d
    float* sd     = als;  // reuse: layer-1 scalar aggregate (als unused until layer 2)

    hipMemsetAsync(zbase, 0, zbytes, stream);

    const int NB = (NNODES + 1023) / 1024;  // 49

    // layer-1 scalars
    k_dots<<<1, 64, 0, stream>>>(W1, as1, ad1, cbuf);
    // CSR build (once; shared by all 3 layers)
    k_hist<<<(ETOT + 255) / 256, 256, 0, stream>>>(ei, cnt);
    k_scanA<<<NB, 256, 0, stream>>>(cnt, tmp, bsums, NNODES);
    k_scanB<<<1, 64, 0, stream>>>(bsums, boffs, NB);
    k_scanC<<<NB, 256, 0, stream>>>(tmp, boffs, rp, NNODES);
    k_scatter<<<(ETOT + 255) / 256, 256, 0, stream>>>(ei, rp, cur, ssrc);

    // ---- layer 1 (rank-1 xp: aggregation is scalar) ----
    k_l1<<<(NNODES + 255) / 256, 256, 0, stream>>>(x, rp, ssrc, cbuf, sd);
    k_out1<<<(NNODES * 32 + 255) / 256, 256, 0, stream>>>(sd, W1, b1, bufA);

    // ---- layer 2 ----
    k_gemm<<<(NNODES + 63) / 64, 256, 0, stream>>>(bufA, W2, bufB, NNODES);
    k_al<<<(NNODES + 3) / 4, 256, 0, stream>>>(bufB, as2, ad2, als, ald);
    k_agg<<<(NNODES + 3) / 4, 256, 0, stream>>>(bufB, als, ald, rp, ssrc, b2, bufA);

    // ---- layer 3 ----
    k_gemm<<<(NNODES + 63) / 64, 256, 0, stream>>>(bufA, W3, bufB, NNODES);
    k_al<<<(NNODES + 3) / 4, 256, 0, stream>>>(bufB, as3, ad3, als, ald);
    k_agg<<<(NNODES + 3) / 4, 256, 0, stream>>>(bufB, als, ald, rp, ssrc, b3, bufA);

    // ---- pool + final ----
    k_pool<<<(NNODES + 3) / 4, 256, 0, stream>>>(bufA, batch, pool, gcnt);
    k_final<<<1, 128, 0, stream>>>(pool, gcnt, Wlin, blin, out);
}

// Round 2
// 442.247 us; speedup vs baseline: 1.8452x; 1.8452x over previous
//
#include <hip/hip_runtime.h>
#include <hip/hip_bf16.h>
#include <math.h>

#define NNODES 50000
#define NEDGES 600000
#define ETOT   (NEDGES + NNODES)
#define HID    128
#define NGRAPH 64
#define SLOPE  0.2f

// ---------- wave (64-lane) reductions ----------
__device__ __forceinline__ float wave_sum(float v) {
    #pragma unroll
    for (int m = 32; m >= 1; m >>= 1) v += __shfl_xor(v, m, 64);
    return v;
}
__device__ __forceinline__ float wave_max(float v) {
    #pragma unroll
    for (int m = 32; m >= 1; m >>= 1) v = fmaxf(v, __shfl_xor(v, m, 64));
    return v;
}

// ---------- c_s = W1 . as1, c_d = W1 . ad1 (layer-1 scalars) ----------
__global__ void k_dots(const float* __restrict__ W1, const float* __restrict__ as1,
                       const float* __restrict__ ad1, float* __restrict__ cbuf) {
    int l = threadIdx.x;  // 64 threads
    float w0 = W1[l], w1 = W1[l + 64];
    float ds = w0 * as1[l] + w1 * as1[l + 64];
    float dd = w0 * ad1[l] + w1 * ad1[l + 64];
    ds = wave_sum(ds); dd = wave_sum(dd);
    if (l == 0) { cbuf[0] = ds; cbuf[1] = dd; }
}

// ---------- CSR build: histogram over dst ----------
__global__ void k_hist(const int* __restrict__ ei, int* __restrict__ cnt) {
    int e = blockIdx.x * blockDim.x + threadIdx.x;
    if (e >= ETOT) return;
    int d = (e < NEDGES) ? ei[NEDGES + e] : (e - NEDGES);
    atomicAdd(&cnt[d], 1);
}

// ---------- scan stage A: per-1024-chunk exclusive scan ----------
__global__ void k_scanA(const int* __restrict__ cnt, int* __restrict__ tmp,
                        int* __restrict__ blockSums, int n) {
    __shared__ int warpSums[4];
    int t = threadIdx.x;                  // 256 threads
    int base = blockIdx.x * 1024 + t * 4;
    int v0 = (base + 0 < n) ? cnt[base + 0] : 0;
    int v1 = (base + 1 < n) ? cnt[base + 1] : 0;
    int v2 = (base + 2 < n) ? cnt[base + 2] : 0;
    int v3 = (base + 3 < n) ? cnt[base + 3] : 0;
    // inclusive within thread
    v1 += v0; v2 += v1; v3 += v2;
    int tsum = v3;
    int lane = t & 63, w = t >> 6;
    int sc = tsum;
    #pragma unroll
    for (int d = 1; d < 64; d <<= 1) {
        int o = __shfl_up(sc, d, 64);
        if (lane >= d) sc += o;
    }
    if (lane == 63) warpSums[w] = sc;
    __syncthreads();
    int woff = 0;
    for (int i = 0; i < w; i++) woff += warpSums[i];
    int texcl = woff + sc - tsum;  // exclusive prefix for this thread's first element
    if (base + 0 < n) tmp[base + 0] = texcl;
    if (base + 1 < n) tmp[base + 1] = texcl + v0;
    if (base + 2 < n) tmp[base + 2] = texcl + v1;
    if (base + 3 < n) tmp[base + 3] = texcl + v2;
    if (t == 255) blockSums[blockIdx.x] = woff + sc;
}

// ---------- scan stage B: serial scan of block sums ----------
__global__ void k_scanB(const int* __restrict__ bs, int* __restrict__ bo, int nb) {
    if (threadIdx.x == 0) {
        int acc = 0;
        for (int i = 0; i < nb; i++) { bo[i] = acc; acc += bs[i]; }
    }
}

// ---------- scan stage C: add block offsets -> row_ptr ----------
__global__ void k_scanC(const int* __restrict__ tmp, const int* __restrict__ bo,
                        int* __restrict__ rp, int n) {
    int t = threadIdx.x;
    int base = blockIdx.x * 1024 + t * 4;
    int add = bo[blockIdx.x];
    #pragma unroll
    for (int j = 0; j < 4; j++)
        if (base + j < n) rp[base + j] = tmp[base + j] + add;
    if (blockIdx.x == 0 && t == 0) rp[n] = ETOT;
}

// ---------- scatter edges into dst-grouped order ----------
__global__ void k_scatter(const int* __restrict__ ei, const int* __restrict__ rp,
                          int* __restrict__ cur, int* __restrict__ ssrc) {
    int e = blockIdx.x * blockDim.x + threadIdx.x;
    if (e >= ETOT) return;
    int s, d;
    if (e < NEDGES) { s = ei[e]; d = ei[NEDGES + e]; }
    else            { s = e - NEDGES; d = s; }
    int pos = rp[d] + atomicAdd(&cur[d], 1);
    ssrc[pos] = s;
}

// ---------- layer-1 aggregation (scalar per dst) ----------
__global__ void k_l1(const float* __restrict__ x, const int* __restrict__ rp,
                     const int* __restrict__ ssrc, const float* __restrict__ cbuf,
                     float* __restrict__ sd) {
    int d = blockIdx.x * blockDim.x + threadIdx.x;
    if (d >= NNODES) return;
    float cs = cbuf[0], cd = cbuf[1];
    float ald = x[d] * cd;
    int beg = rp[d], end = rp[d + 1];
    float m = -3.4e38f;
    for (int e = beg; e < end; e++) {
        float a = fmaf(x[ssrc[e]], cs, ald);
        a = a > 0.f ? a : SLOPE * a;
        m = fmaxf(m, a);
    }
    float den = 0.f, acc = 0.f;
    for (int e = beg; e < end; e++) {
        float xs = x[ssrc[e]];
        float a = fmaf(xs, cs, ald);
        a = a > 0.f ? a : SLOPE * a;
        float w = __expf(a - m);
        den += w; acc += w * xs;
    }
    sd[d] = acc / den;
}

// ---------- layer-1 expand: h1[i,j] = relu(s_i * W1[j] + b1[j]) ----------
__global__ void k_out1(const float* __restrict__ sd, const float* __restrict__ W1,
                       const float* __restrict__ b1, float* __restrict__ h) {
    int idx = blockIdx.x * blockDim.x + threadIdx.x;  // NNODES*32 threads
    int i = idx >> 5, c4 = (idx & 31) * 4;
    if (i >= NNODES) return;
    float s = sd[i];
    float4 w = *(const float4*)(W1 + c4);
    float4 b = *(const float4*)(b1 + c4);
    float4 o;
    o.x = fmaxf(fmaf(s, w.x, b.x), 0.f);
    o.y = fmaxf(fmaf(s, w.y, b.y), 0.f);
    o.z = fmaxf(fmaf(s, w.z, b.z), 0.f);
    o.w = fmaxf(fmaf(s, w.w, b.w), 0.f);
    *(float4*)(h + i * HID + c4) = o;
}

// ---------- fp32 GEMM: C[nrows x 128] = H[nrows x 128] * W[128 x 128] ----------
__launch_bounds__(256)
__global__ void k_gemm(const float* __restrict__ H, const float* __restrict__ W,
                       float* __restrict__ C, int nrows) {
    __shared__ float Hs[64 * 16];
    __shared__ float Ws[16 * 128];
    int t = threadIdx.x;
    int tx = t & 31, ty = t >> 5;
    int row0 = blockIdx.x * 64;
    float acc[8][4];
    #pragma unroll
    for (int i = 0; i < 8; i++)
        #pragma unroll
        for (int j = 0; j < 4; j++) acc[i][j] = 0.f;

    for (int kc = 0; kc < 128; kc += 16) {
        {   // stage H tile 64x16
            int r = t >> 2, kg = (t & 3) * 4;
            int gr = row0 + r;
            float4 v = make_float4(0.f, 0.f, 0.f, 0.f);
            if (gr < nrows) v = *(const float4*)(H + gr * 128 + kc + kg);
            *(float4*)(Hs + r * 16 + kg) = v;
        }
        #pragma unroll
        for (int q = 0; q < 2; q++) {  // stage W tile 16x128
            int f = t + q * 256;
            int kk = f >> 5, c4 = (f & 31) * 4;
            *(float4*)(Ws + kk * 128 + c4) = *(const float4*)(W + (kc + kk) * 128 + c4);
        }
        __syncthreads();
        #pragma unroll
        for (int kk = 0; kk < 16; kk++) {
            float4 wv = *(const float4*)(Ws + kk * 128 + tx * 4);
            #pragma unroll
            for (int i = 0; i < 8; i++) {
                float hv = Hs[(ty * 8 + i) * 16 + kk];
                acc[i][0] = fmaf(hv, wv.x, acc[i][0]);
                acc[i][1] = fmaf(hv, wv.y, acc[i][1]);
                acc[i][2] = fmaf(hv, wv.z, acc[i][2]);
                acc[i][3] = fmaf(hv, wv.w, acc[i][3]);
            }
        }
        __syncthreads();
    }
    #pragma unroll
    for (int i = 0; i < 8; i++) {
        int gr = row0 + ty * 8 + i;
        if (gr < nrows) {
            float4 o = make_float4(acc[i][0], acc[i][1], acc[i][2], acc[i][3]);
            *(float4*)(C + gr * 128 + tx * 4) = o;
        }
    }
}

// ---------- attention logits: al_s = xp.a_src, al_d = xp.a_dst (wave/node) ----------
__global__ void k_al(const float* __restrict__ xp, const float* __restrict__ as_,
                     const float* __restrict__ ad_, float* __restrict__ als,
                     float* __restrict__ ald) {
    int wid = threadIdx.x >> 6, lane = threadIdx.x & 63;
    int node = blockIdx.x * 4 + wid;
    if (node >= NNODES) return;
    float v0 = xp[node * 128 + lane], v1 = xp[node * 128 + 64 + lane];
    float ds = v0 * as_[lane] + v1 * as_[lane + 64];
    float dd = v0 * ad_[lane] + v1 * ad_[lane + 64];
    ds = wave_sum(ds); dd = wave_sum(dd);
    if (lane == 0) { als[node] = ds; ald[node] = dd; }
}

// ---------- GAT aggregation (wave per dst), fused +b and relu ----------
__launch_bounds__(256)
__global__ void k_agg(const float* __restrict__ xp, const float* __restrict__ als,
                      const float* __restrict__ ald, const int* __restrict__ rp,
                      const int* __restrict__ ssrc, const float* __restrict__ b,
                      float* __restrict__ hout) {
    int wid = threadIdx.x >> 6, lane = threadIdx.x & 63;
    int d = blockIdx.x * 4 + wid;
    if (d >= NNODES) return;
    int beg = rp[d], end = rp[d + 1];
    float adv = ald[d];
    // phase 1: max over incoming alphas (lanes parallel over edges)
    float m = -3.4e38f;
    for (int e = beg + lane; e < end; e += 64) {
        float a = als[ssrc[e]] + adv;
        a = a > 0.f ? a : SLOPE * a;
        m = fmaxf(m, a);
    }
    m = wave_max(m);
    // phase 2: serial over edges, lanes cover 128 channels as float2
    float den = 0.f;
    float2 acc = make_float2(0.f, 0.f);
    for (int e = beg; e < end; e++) {
        int s = ssrc[e];
        float a = als[s] + adv;
        a = a > 0.f ? a : SLOPE * a;
        float w = __expf(a - m);
        den += w;
        float2 v = *(const float2*)(xp + s * 128 + lane * 2);
        acc.x = fmaf(w, v.x, acc.x);
        acc.y = fmaf(w, v.y, acc.y);
    }
    float inv = 1.f / den;
    float2 bb = *(const float2*)(b + lane * 2);
    float2 o;
    o.x = fmaxf(fmaf(acc.x, inv, bb.x), 0.f);
    o.y = fmaxf(fmaf(acc.y, inv, bb.y), 0.f);
    *(float2*)(hout + d * 128 + lane * 2) = o;
}

// ---------- global mean pool: batch is SORTED -> per-wave register accumulation,
//            atomic flush only on graph-boundary crossings ----------
#define PNW 64  // nodes per wave
__global__ void k_pool(const float* __restrict__ h, const int* __restrict__ batch,
                       float* __restrict__ pool, float* __restrict__ gcnt) {
    int wid = threadIdx.x >> 6, lane = threadIdx.x & 63;
    int base = (blockIdx.x * 4 + wid) * PNW;
    if (base >= NNODES) return;
    int end = base + PNW; if (end > NNODES) end = NNODES;
    float2 acc = make_float2(0.f, 0.f);
    float cnt = 0.f;
    int curg = batch[base];
    for (int i = base; i < end; i++) {
        int g = batch[i];
        if (g != curg) {
            atomicAdd(&pool[curg * 128 + lane * 2], acc.x);
            atomicAdd(&pool[curg * 128 + lane * 2 + 1], acc.y);
            if (lane == 0) atomicAdd(&gcnt[curg], cnt);
            curg = g; acc = make_float2(0.f, 0.f); cnt = 0.f;
        }
        float2 v = *(const float2*)(h + (size_t)i * 128 + lane * 2);
        acc.x += v.x; acc.y += v.y; cnt += 1.f;
    }
    atomicAdd(&pool[curg * 128 + lane * 2], acc.x);
    atomicAdd(&pool[curg * 128 + lane * 2 + 1], acc.y);
    if (lane == 0) atomicAdd(&gcnt[curg], cnt);
}

// ---------- final linear + sigmoid ----------
__global__ void k_final(const float* __restrict__ pool, const float* __restrict__ gcnt,
                        const float* __restrict__ Wlin, const float* __restrict__ blin,
                        float* __restrict__ out) {
    int t = threadIdx.x;  // 128 threads
    int g = t >> 1, k = t & 1;
    float c = fmaxf(gcnt[g], 1.f);
    float acc = 0.f;
    for (int j = 0; j < 128; j++) acc += pool[g * 128 + j] * Wlin[j * 2 + k];
    acc = acc / c + blin[k];
    out[g * 2 + k] = 1.f / (1.f + __expf(-acc));
}

extern "C" void kernel_launch(void* const* d_in, const int* in_sizes, int n_in,
                              void* d_out, int out_size, void* d_ws, size_t ws_size,
                              hipStream_t stream) {
    const float* x    = (const float*)d_in[0];
    const int*   ei   = (const int*)d_in[1];
    const int*   batch= (const int*)d_in[2];
    const float* W1   = (const float*)d_in[3];
    const float* as1  = (const float*)d_in[4];
    const float* ad1  = (const float*)d_in[5];
    const float* b1   = (const float*)d_in[6];
    const float* W2   = (const float*)d_in[7];
    const float* as2  = (const float*)d_in[8];
    const float* ad2  = (const float*)d_in[9];
    const float* b2   = (const float*)d_in[10];
    const float* W3   = (const float*)d_in[11];
    const float* as3  = (const float*)d_in[12];
    const float* ad3  = (const float*)d_in[13];
    const float* b3   = (const float*)d_in[14];
    const float* Wlin = (const float*)d_in[15];
    const float* blin = (const float*)d_in[16];
    float* out = (float*)d_out;

    // ---- workspace layout (bytes) ----
    char* ws = (char*)d_ws;
    size_t off = 0;
    float* bufA   = (float*)(ws + off); off += (size_t)NNODES * HID * 4;   // 25.6 MB
    float* bufB   = (float*)(ws + off); off += (size_t)NNODES * HID * 4;   // 25.6 MB
    float* als    = (float*)(ws + off); off += NNODES * 4;
    float* ald    = (float*)(ws + off); off += NNODES * 4;
    int*   rp     = (int*)(ws + off);   off += (NNODES + 16) * 4;
    int*   tmp    = (int*)(ws + off);   off += NNODES * 4;
    int*   bsums  = (int*)(ws + off);   off += 64 * 4;
    int*   boffs  = (int*)(ws + off);   off += 64 * 4;
    int*   ssrc   = (int*)(ws + off);   off += (size_t)ETOT * 4;
    // zeroed region (single memset): cnt, cur, pool, gcnt
    char*  zbase  = ws + off;
    int*   cnt    = (int*)(ws + off);   off += NNODES * 4;
    int*   cur    = (int*)(ws + off);   off += NNODES * 4;
    float* pool   = (float*)(ws + off); off += NGRAPH * HID * 4;
    float* gcnt   = (float*)(ws + off); off += 64 * 4;
    size_t zbytes = (size_t)((char*)(ws + off) - zbase);
    float* cbuf   = (float*)(ws + off); off += 64;   // c_s, c_d
    float* sd     = als;  // reuse: layer-1 scalar aggregate (als unused until layer 2)

    hipMemsetAsync(zbase, 0, zbytes, stream);

    const int NB = (NNODES + 1023) / 1024;  // 49

    // layer-1 scalars
    k_dots<<<1, 64, 0, stream>>>(W1, as1, ad1, cbuf);
    // CSR build (once; shared by all 3 layers)
    k_hist<<<(ETOT + 255) / 256, 256, 0, stream>>>(ei, cnt);
    k_scanA<<<NB, 256, 0, stream>>>(cnt, tmp, bsums, NNODES);
    k_scanB<<<1, 64, 0, stream>>>(bsums, boffs, NB);
    k_scanC<<<NB, 256, 0, stream>>>(tmp, boffs, rp, NNODES);
    k_scatter<<<(ETOT + 255) / 256, 256, 0, stream>>>(ei, rp, cur, ssrc);

    // ---- layer 1 (rank-1 xp: aggregation is scalar) ----
    k_l1<<<(NNODES + 255) / 256, 256, 0, stream>>>(x, rp, ssrc, cbuf, sd);
    k_out1<<<(NNODES * 32 + 255) / 256, 256, 0, stream>>>(sd, W1, b1, bufA);

    // ---- layer 2 ----
    k_gemm<<<(NNODES + 63) / 64, 256, 0, stream>>>(bufA, W2, bufB, NNODES);
    k_al<<<(NNODES + 3) / 4, 256, 0, stream>>>(bufB, as2, ad2, als, ald);
    k_agg<<<(NNODES + 3) / 4, 256, 0, stream>>>(bufB, als, ald, rp, ssrc, b2, bufA);

    // ---- layer 3 ----
    k_gemm<<<(NNODES + 63) / 64, 256, 0, stream>>>(bufA, W3, bufB, NNODES);
    k_al<<<(NNODES + 3) / 4, 256, 0, stream>>>(bufB, as3, ad3, als, ald);
    k_agg<<<(NNODES + 3) / 4, 256, 0, stream>>>(bufB, als, ald, rp, ssrc, b3, bufA);

    // ---- pool + final ----
    k_pool<<<(NNODES + 4 * PNW - 1) / (4 * PNW), 256, 0, stream>>>(bufA, batch, pool, gcnt);
    k_final<<<1, 128, 0, stream>>>(pool, gcnt, Wlin, blin, out);
}

// Round 3
// 361.751 us; speedup vs baseline: 2.2558x; 1.2225x over previous
//
#include <hip/hip_runtime.h>
#include <hip/hip_bf16.h>
#include <math.h>

#define NNODES 50000
#define NEDGES 600000
#define ETOT   (NEDGES + NNODES)
#define HID    128
#define NGRAPH 64
#define SLOPE  0.2f

// ---------- wave (64-lane) reductions ----------
__device__ __forceinline__ float wave_sum(float v) {
    #pragma unroll
    for (int m = 32; m >= 1; m >>= 1) v += __shfl_xor(v, m, 64);
    return v;
}
__device__ __forceinline__ float wave_max(float v) {
    #pragma unroll
    for (int m = 32; m >= 1; m >>= 1) v = fmaxf(v, __shfl_xor(v, m, 64));
    return v;
}

// ---------- CSR build: histogram over dst ----------
__global__ void k_hist(const int* __restrict__ ei, int* __restrict__ cnt) {
    int e = blockIdx.x * blockDim.x + threadIdx.x;
    if (e >= ETOT) return;
    int d = (e < NEDGES) ? ei[NEDGES + e] : (e - NEDGES);
    atomicAdd(&cnt[d], 1);
}

// ---------- scan stage A: per-1024-chunk exclusive scan ----------
__global__ void k_scanA(const int* __restrict__ cnt, int* __restrict__ tmp,
                        int* __restrict__ blockSums, int n) {
    __shared__ int warpSums[4];
    int t = threadIdx.x;                  // 256 threads
    int base = blockIdx.x * 1024 + t * 4;
    int v0 = (base + 0 < n) ? cnt[base + 0] : 0;
    int v1 = (base + 1 < n) ? cnt[base + 1] : 0;
    int v2 = (base + 2 < n) ? cnt[base + 2] : 0;
    int v3 = (base + 3 < n) ? cnt[base + 3] : 0;
    v1 += v0; v2 += v1; v3 += v2;
    int tsum = v3;
    int lane = t & 63, w = t >> 6;
    int sc = tsum;
    #pragma unroll
    for (int d = 1; d < 64; d <<= 1) {
        int o = __shfl_up(sc, d, 64);
        if (lane >= d) sc += o;
    }
    if (lane == 63) warpSums[w] = sc;
    __syncthreads();
    int woff = 0;
    for (int i = 0; i < w; i++) woff += warpSums[i];
    int texcl = woff + sc - tsum;
    if (base + 0 < n) tmp[base + 0] = texcl;
    if (base + 1 < n) tmp[base + 1] = texcl + v0;
    if (base + 2 < n) tmp[base + 2] = texcl + v1;
    if (base + 3 < n) tmp[base + 3] = texcl + v2;
    if (t == 255) blockSums[blockIdx.x] = woff + sc;
}

// ---------- scan stage B (serial block-sum scan) + layer-1 dot scalars ----------
__global__ void k_scanB_dots(const int* __restrict__ bs, int* __restrict__ bo, int nb,
                             const float* __restrict__ W1, const float* __restrict__ as1,
                             const float* __restrict__ ad1, float* __restrict__ cbuf) {
    int l = threadIdx.x;  // 64 threads
    float w0 = W1[l], w1 = W1[l + 64];
    float ds = w0 * as1[l] + w1 * as1[l + 64];
    float dd = w0 * ad1[l] + w1 * ad1[l + 64];
    ds = wave_sum(ds); dd = wave_sum(dd);
    if (l == 0) {
        cbuf[0] = ds; cbuf[1] = dd;
        int acc = 0;
        for (int i = 0; i < nb; i++) { bo[i] = acc; acc += bs[i]; }
    }
}

// ---------- scan stage C: add block offsets -> row_ptr ----------
__global__ void k_scanC(const int* __restrict__ tmp, const int* __restrict__ bo,
                        int* __restrict__ rp, int n) {
    int t = threadIdx.x;
    int base = blockIdx.x * 1024 + t * 4;
    int add = bo[blockIdx.x];
    #pragma unroll
    for (int j = 0; j < 4; j++)
        if (base + j < n) rp[base + j] = tmp[base + j] + add;
    if (blockIdx.x == 0 && t == 0) rp[n] = ETOT;
}

// ---------- scatter edges into dst-grouped order ----------
__global__ void k_scatter(const int* __restrict__ ei, const int* __restrict__ rp,
                          int* __restrict__ cur, int* __restrict__ ssrc) {
    int e = blockIdx.x * blockDim.x + threadIdx.x;
    if (e >= ETOT) return;
    int s, d;
    if (e < NEDGES) { s = ei[e]; d = ei[NEDGES + e]; }
    else            { s = e - NEDGES; d = s; }
    int pos = rp[d] + atomicAdd(&cur[d], 1);
    ssrc[pos] = s;
}

// ---------- layer-1 aggregation (wave per dst, lane-parallel edges) ----------
__global__ void k_l1(const float* __restrict__ x, const int* __restrict__ rp,
                     const int* __restrict__ ssrc, const float* __restrict__ cbuf,
                     float* __restrict__ sd) {
    int wid = threadIdx.x >> 6, lane = threadIdx.x & 63;
    int d = blockIdx.x * 4 + wid;
    if (d >= NNODES) return;
    float cs = cbuf[0], cd = cbuf[1];
    float ald = x[d] * cd;
    int beg = rp[d], end = rp[d + 1], deg = end - beg;
    float num, den;
    if (deg <= 64) {
        float xs = 0.f, a = -3.4e38f;
        if (lane < deg) {
            xs = x[ssrc[beg + lane]];
            a = fmaf(xs, cs, ald);
            a = a > 0.f ? a : SLOPE * a;
        }
        float m = wave_max(a);
        float w = (lane < deg) ? __expf(a - m) : 0.f;
        den = wave_sum(w);
        num = wave_sum(w * xs);
    } else {
        float m = -3.4e38f;
        for (int e = beg + lane; e < end; e += 64) {
            float a = fmaf(x[ssrc[e]], cs, ald);
            a = a > 0.f ? a : SLOPE * a;
            m = fmaxf(m, a);
        }
        m = wave_max(m);
        float dl = 0.f, nl = 0.f;
        for (int e = beg + lane; e < end; e += 64) {
            float xs = x[ssrc[e]];
            float a = fmaf(xs, cs, ald);
            a = a > 0.f ? a : SLOPE * a;
            float w = __expf(a - m);
            dl += w; nl += w * xs;
        }
        den = wave_sum(dl); num = wave_sum(nl);
    }
    if (lane == 0) sd[d] = num / den;
}

// ---------- fp32 GEMM: C = H * W, fused attention-logit epilogue.
//            If sd != nullptr, H rows are synthesized as relu(sd[r]*W1[k]+b1[k]).
__launch_bounds__(256)
__global__ void k_gemm(const float* __restrict__ H, const float* __restrict__ sd,
                       const float* __restrict__ W1, const float* __restrict__ b1,
                       const float* __restrict__ W, float* __restrict__ C,
                       const float* __restrict__ av_s, const float* __restrict__ av_d,
                       float* __restrict__ als, float* __restrict__ ald, int nrows) {
    __shared__ float Hs[64 * 16];
    __shared__ float Ws[16 * 128];
    int t = threadIdx.x;
    int tx = t & 31, ty = t >> 5;
    int row0 = blockIdx.x * 64;
    float acc[8][4];
    #pragma unroll
    for (int i = 0; i < 8; i++)
        #pragma unroll
        for (int j = 0; j < 4; j++) acc[i][j] = 0.f;

    for (int kc = 0; kc < 128; kc += 16) {
        {   // stage H tile 64x16
            int r = t >> 2, kg = (t & 3) * 4;
            int gr = row0 + r;
            float4 v = make_float4(0.f, 0.f, 0.f, 0.f);
            if (gr < nrows) {
                if (sd != nullptr) {
                    float s = sd[gr];
                    float4 w1v = *(const float4*)(W1 + kc + kg);
                    float4 b1v = *(const float4*)(b1 + kc + kg);
                    v.x = fmaxf(fmaf(s, w1v.x, b1v.x), 0.f);
                    v.y = fmaxf(fmaf(s, w1v.y, b1v.y), 0.f);
                    v.z = fmaxf(fmaf(s, w1v.z, b1v.z), 0.f);
                    v.w = fmaxf(fmaf(s, w1v.w, b1v.w), 0.f);
                } else {
                    v = *(const float4*)(H + (size_t)gr * 128 + kc + kg);
                }
            }
            *(float4*)(Hs + r * 16 + kg) = v;
        }
        #pragma unroll
        for (int q = 0; q < 2; q++) {  // stage W tile 16x128
            int f = t + q * 256;
            int kk = f >> 5, c4 = (f & 31) * 4;
            *(float4*)(Ws + kk * 128 + c4) = *(const float4*)(W + (kc + kk) * 128 + c4);
        }
        __syncthreads();
        #pragma unroll
        for (int kk = 0; kk < 16; kk++) {
            float4 wv = *(const float4*)(Ws + kk * 128 + tx * 4);
            #pragma unroll
            for (int i = 0; i < 8; i++) {
                float hv = Hs[(ty * 8 + i) * 16 + kk];
                acc[i][0] = fmaf(hv, wv.x, acc[i][0]);
                acc[i][1] = fmaf(hv, wv.y, acc[i][1]);
                acc[i][2] = fmaf(hv, wv.z, acc[i][2]);
                acc[i][3] = fmaf(hv, wv.w, acc[i][3]);
            }
        }
        __syncthreads();
    }
    // epilogue: write C rows + fused al_s/al_d (reduce over the 32 tx lanes)
    float4 asv = *(const float4*)(av_s + tx * 4);
    float4 adv = *(const float4*)(av_d + tx * 4);
    #pragma unroll
    for (int i = 0; i < 8; i++) {
        int gr = row0 + ty * 8 + i;
        float ds = acc[i][0] * asv.x + acc[i][1] * asv.y + acc[i][2] * asv.z + acc[i][3] * asv.w;
        float dd = acc[i][0] * adv.x + acc[i][1] * adv.y + acc[i][2] * adv.z + acc[i][3] * adv.w;
        #pragma unroll
        for (int m = 16; m >= 1; m >>= 1) {
            ds += __shfl_xor(ds, m, 64);
            dd += __shfl_xor(dd, m, 64);
        }
        if (gr < nrows) {
            float4 o = make_float4(acc[i][0], acc[i][1], acc[i][2], acc[i][3]);
            *(float4*)(C + (size_t)gr * 128 + tx * 4) = o;
            if (tx == 0) { als[gr] = ds; ald[gr] = dd; }
        }
    }
}

// ---------- GAT aggregation (wave per dst): lane-parallel weight precompute
//            into LDS, then 4x-unrolled channel gather ----------
__launch_bounds__(256)
__global__ void k_agg(const float* __restrict__ xp, const float* __restrict__ als,
                      const float* __restrict__ ald_, const int* __restrict__ rp,
                      const int* __restrict__ ssrc, const float* __restrict__ b,
                      float* __restrict__ hout) {
    __shared__ float2 swbuf[4][64];   // {w, src-as-float-bits} per wave
    int wid = threadIdx.x >> 6, lane = threadIdx.x & 63;
    int d = blockIdx.x * 4 + wid;
    if (d >= NNODES) return;
    int beg = rp[d], end = rp[d + 1], deg = end - beg;
    float adv = ald_[d];
    float den;
    float2 acc = make_float2(0.f, 0.f);

    if (deg <= 64) {
        int s_l = 0;
        float a_l = -3.4e38f;
        if (lane < deg) {
            s_l = ssrc[beg + lane];
            float a = als[s_l] + adv;
            a_l = a > 0.f ? a : SLOPE * a;
        }
        float m = wave_max(a_l);
        float w_l = (lane < deg) ? __expf(a_l - m) : 0.f;
        den = wave_sum(w_l);
        swbuf[wid][lane] = make_float2(w_l, __int_as_float(s_l));
        // same-wave LDS write->read; compiler inserts the lgkmcnt wait
        int k = 0;
        for (; k + 4 <= deg; k += 4) {
            float2 p0 = swbuf[wid][k + 0];
            float2 p1 = swbuf[wid][k + 1];
            float2 p2 = swbuf[wid][k + 2];
            float2 p3 = swbuf[wid][k + 3];
            const float2* r0 = (const float2*)(xp + (size_t)__float_as_int(p0.y) * 128 + lane * 2);
            const float2* r1 = (const float2*)(xp + (size_t)__float_as_int(p1.y) * 128 + lane * 2);
            const float2* r2 = (const float2*)(xp + (size_t)__float_as_int(p2.y) * 128 + lane * 2);
            const float2* r3 = (const float2*)(xp + (size_t)__float_as_int(p3.y) * 128 + lane * 2);
            float2 v0 = *r0, v1 = *r1, v2 = *r2, v3 = *r3;
            acc.x = fmaf(p0.x, v0.x, acc.x); acc.y = fmaf(p0.x, v0.y, acc.y);
            acc.x = fmaf(p1.x, v1.x, acc.x); acc.y = fmaf(p1.x, v1.y, acc.y);
            acc.x = fmaf(p2.x, v2.x, acc.x); acc.y = fmaf(p2.x, v2.y, acc.y);
            acc.x = fmaf(p3.x, v3.x, acc.x); acc.y = fmaf(p3.x, v3.y, acc.y);
        }
        for (; k < deg; k++) {
            float2 p = swbuf[wid][k];
            float2 v = *(const float2*)(xp + (size_t)__float_as_int(p.y) * 128 + lane * 2);
            acc.x = fmaf(p.x, v.x, acc.x); acc.y = fmaf(p.x, v.y, acc.y);
        }
    } else {
        // rare fallback: deg > 64
        float m = -3.4e38f;
        for (int e = beg + lane; e < end; e += 64) {
            float a = als[ssrc[e]] + adv;
            a = a > 0.f ? a : SLOPE * a;
            m = fmaxf(m, a);
        }
        m = wave_max(m);
        den = 0.f;
        for (int e = beg; e < end; e++) {
            int s = ssrc[e];
            float a = als[s] + adv;
            a = a > 0.f ? a : SLOPE * a;
            float w = __expf(a - m);
            den += w;
            float2 v = *(const float2*)(xp + (size_t)s * 128 + lane * 2);
            acc.x = fmaf(w, v.x, acc.x);
            acc.y = fmaf(w, v.y, acc.y);
        }
    }
    float inv = 1.f / den;
    float2 bb = *(const float2*)(b + lane * 2);
    float2 o;
    o.x = fmaxf(fmaf(acc.x, inv, bb.x), 0.f);
    o.y = fmaxf(fmaf(acc.y, inv, bb.y), 0.f);
    *(float2*)(hout + (size_t)d * 128 + lane * 2) = o;
}

// ---------- global mean pool: batch sorted -> register accumulate, flush on crossing ----------
#define PNW 64  // nodes per wave
__global__ void k_pool(const float* __restrict__ h, const int* __restrict__ batch,
                       float* __restrict__ pool, float* __restrict__ gcnt) {
    int wid = threadIdx.x >> 6, lane = threadIdx.x & 63;
    int base = (blockIdx.x * 4 + wid) * PNW;
    if (base >= NNODES) return;
    int end = base + PNW; if (end > NNODES) end = NNODES;
    float2 acc = make_float2(0.f, 0.f);
    float cnt = 0.f;
    int curg = batch[base];
    for (int i = base; i < end; i++) {
        int g = batch[i];
        if (g != curg) {
            atomicAdd(&pool[curg * 128 + lane * 2], acc.x);
            atomicAdd(&pool[curg * 128 + lane * 2 + 1], acc.y);
            if (lane == 0) atomicAdd(&gcnt[curg], cnt);
            curg = g; acc = make_float2(0.f, 0.f); cnt = 0.f;
        }
        float2 v = *(const float2*)(h + (size_t)i * 128 + lane * 2);
        acc.x += v.x; acc.y += v.y; cnt += 1.f;
    }
    atomicAdd(&pool[curg * 128 + lane * 2], acc.x);
    atomicAdd(&pool[curg * 128 + lane * 2 + 1], acc.y);
    if (lane == 0) atomicAdd(&gcnt[curg], cnt);
}

// ---------- final linear + sigmoid ----------
__global__ void k_final(const float* __restrict__ pool, const float* __restrict__ gcnt,
                        const float* __restrict__ Wlin, const float* __restrict__ blin,
                        float* __restrict__ out) {
    int t = threadIdx.x;  // 128 threads
    int g = t >> 1, k = t & 1;
    float c = fmaxf(gcnt[g], 1.f);
    float acc = 0.f;
    for (int j = 0; j < 128; j++) acc += pool[g * 128 + j] * Wlin[j * 2 + k];
    acc = acc / c + blin[k];
    out[g * 2 + k] = 1.f / (1.f + __expf(-acc));
}

extern "C" void kernel_launch(void* const* d_in, const int* in_sizes, int n_in,
                              void* d_out, int out_size, void* d_ws, size_t ws_size,
                              hipStream_t stream) {
    const float* x    = (const float*)d_in[0];
    const int*   ei   = (const int*)d_in[1];
    const int*   batch= (const int*)d_in[2];
    const float* W1   = (const float*)d_in[3];
    const float* as1  = (const float*)d_in[4];
    const float* ad1  = (const float*)d_in[5];
    const float* b1   = (const float*)d_in[6];
    const float* W2   = (const float*)d_in[7];
    const float* as2  = (const float*)d_in[8];
    const float* ad2  = (const float*)d_in[9];
    const float* b2   = (const float*)d_in[10];
    const float* W3   = (const float*)d_in[11];
    const float* as3  = (const float*)d_in[12];
    const float* ad3  = (const float*)d_in[13];
    const float* b3   = (const float*)d_in[14];
    const float* Wlin = (const float*)d_in[15];
    const float* blin = (const float*)d_in[16];
    float* out = (float*)d_out;

    // ---- workspace layout ----
    char* ws = (char*)d_ws;
    size_t off = 0;
    float* bufA   = (float*)(ws + off); off += (size_t)NNODES * HID * 4;
    float* bufB   = (float*)(ws + off); off += (size_t)NNODES * HID * 4;
    float* als    = (float*)(ws + off); off += NNODES * 4;
    float* ald    = (float*)(ws + off); off += NNODES * 4;
    float* sd     = (float*)(ws + off); off += NNODES * 4;
    int*   rp     = (int*)(ws + off);   off += (NNODES + 16) * 4;
    int*   tmp    = (int*)(ws + off);   off += NNODES * 4;
    int*   bsums  = (int*)(ws + off);   off += 64 * 4;
    int*   boffs  = (int*)(ws + off);   off += 64 * 4;
    int*   ssrc   = (int*)(ws + off);   off += (size_t)ETOT * 4;
    char*  zbase  = ws + off;
    int*   cnt    = (int*)(ws + off);   off += NNODES * 4;
    int*   cur    = (int*)(ws + off);   off += NNODES * 4;
    float* pool   = (float*)(ws + off); off += NGRAPH * HID * 4;
    float* gcnt   = (float*)(ws + off); off += 64 * 4;
    size_t zbytes = (size_t)((char*)(ws + off) - zbase);
    float* cbuf   = (float*)(ws + off); off += 64;

    hipMemsetAsync(zbase, 0, zbytes, stream);

    const int NB = (NNODES + 1023) / 1024;  // 49

    // CSR build (shared by all layers) + layer-1 scalars
    k_hist<<<(ETOT + 255) / 256, 256, 0, stream>>>(ei, cnt);
    k_scanA<<<NB, 256, 0, stream>>>(cnt, tmp, bsums, NNODES);
    k_scanB_dots<<<1, 64, 0, stream>>>(bsums, boffs, NB, W1, as1, ad1, cbuf);
    k_scanC<<<NB, 256, 0, stream>>>(tmp, boffs, rp, NNODES);
    k_scatter<<<(ETOT + 255) / 256, 256, 0, stream>>>(ei, rp, cur, ssrc);

    // ---- layer 1 (rank-1 xp: aggregation is scalar) ----
    k_l1<<<(NNODES + 3) / 4, 256, 0, stream>>>(x, rp, ssrc, cbuf, sd);

    // ---- layer 2 (h1 synthesized from sd inside GEMM; fused al epilogue) ----
    k_gemm<<<(NNODES + 63) / 64, 256, 0, stream>>>(nullptr, sd, W1, b1, W2, bufB,
                                                   as2, ad2, als, ald, NNODES);
    k_agg<<<(NNODES + 3) / 4, 256, 0, stream>>>(bufB, als, ald, rp, ssrc, b2, bufA);

    // ---- layer 3 ----
    k_gemm<<<(NNODES + 63) / 64, 256, 0, stream>>>(bufA, nullptr, nullptr, nullptr, W3, bufB,
                                                   as3, ad3, als, ald, NNODES);
    k_agg<<<(NNODES + 3) / 4, 256, 0, stream>>>(bufB, als, ald, rp, ssrc, b3, bufA);

    // ---- pool + final ----
    k_pool<<<(NNODES + 4 * PNW - 1) / (4 * PNW), 256, 0, stream>>>(bufA, batch, pool, gcnt);
    k_final<<<1, 128, 0, stream>>>(pool, gcnt, Wlin, blin, out);
}